// Round 10
// baseline (262.973 us; speedup 1.0000x reference)
//
#include <hip/hip_runtime.h>
#include <hip/hip_bf16.h>

// Problem constants (BertSelfAttention_979252544303)
#define SEQ   2048
#define BATCH 2
#define HID   1024
#define NHEAD 16
#define HDIM  64
#define BH    (BATCH * NHEAD)   // 32 flattened heads

using short4v  = __attribute__((ext_vector_type(4))) short;
using short8   = __attribute__((ext_vector_type(8))) short;
using floatx4  = __attribute__((ext_vector_type(4))) float;

#define LOG2E 1.44269504f
#define SCALE_LOG2E (0.125f * LOG2E)   // (1/sqrt(64)) * log2(e)

// attn LDS pitch 72 (pitch 80 doubled SQ_LDS_BANK_CONFLICT via 32-lane-phase
// b64-read aliasing — measured R8; and conflicts are off the critical path)
#define KVP 72

// float -> bf16 (RNE)
static __device__ __forceinline__ unsigned short f2bf(float f) {
    unsigned int u = __builtin_bit_cast(unsigned int, f);
    u += 0x7fffu + ((u >> 16) & 1u);
    return (unsigned short)(u >> 16);
}

// D = A(16x16 bf16) * B(16x16 bf16) + C  — per-wave MFMA, K=16
static __device__ __forceinline__ floatx4 mfma16x16x16(
    short4v a, short4v b, floatx4 c) {
#if __has_builtin(__builtin_amdgcn_mfma_f32_16x16x16bf16_1k)
    return __builtin_amdgcn_mfma_f32_16x16x16bf16_1k(a, b, c, 0, 0, 0);
#else
    floatx4 d;
    asm volatile("v_mfma_f32_16x16x16_bf16 %0, %1, %2, %3"
                 : "=v"(d) : "v"(a), "v"(b), "v"(c));
    return d;
#endif
}

#define GLD16(gp, lp)                                                        \
    __builtin_amdgcn_global_load_lds(                                        \
        (const __attribute__((address_space(1))) void*)(gp),                 \
        (__attribute__((address_space(3))) void*)(lp), 16, 0, 0)

// ---------------------------------------------------------------------------
// Prep 1: x fp32 [4096][1024] -> bf16 (straight). 1 float4 per thread.
// ---------------------------------------------------------------------------
__global__ __launch_bounds__(256) void convert_x(
    const float* __restrict__ x, unsigned short* __restrict__ xb)
{
    const int i = blockIdx.x * 256 + threadIdx.x;
    const float4 v = ((const float4*)x)[i];
    ushort4 o;
    o.x = f2bf(v.x); o.y = f2bf(v.y); o.z = f2bf(v.z); o.w = f2bf(v.w);
    ((ushort4*)xb)[i] = o;
}

// ---------------------------------------------------------------------------
// Prep 2: W fp32 [k][n] -> wt bf16 [n][k], tiled transpose. z selects Q/K/V.
// ---------------------------------------------------------------------------
__global__ __launch_bounds__(256) void transpose_w(
    const float* __restrict__ Wq, const float* __restrict__ Wk,
    const float* __restrict__ Wv, unsigned short* __restrict__ wt)
{
    const float* W = (blockIdx.z == 0) ? Wq : (blockIdx.z == 1) ? Wk : Wv;
    unsigned short* out = wt + (size_t)blockIdx.z * HID * HID;
    __shared__ float tile[32][33];
    const int tx = threadIdx.x & 31, ty = threadIdx.x >> 5;
    const int bx = blockIdx.x * 32, by = blockIdx.y * 32;
    #pragma unroll
    for (int j = 0; j < 4; ++j)
        tile[ty + j * 8][tx] = W[(size_t)(by + ty + j * 8) * HID + bx + tx];
    __syncthreads();
    #pragma unroll
    for (int j = 0; j < 4; ++j)
        out[(size_t)(bx + ty + j * 8) * HID + by + tx] = f2bf(tile[tx][ty + j * 8]);
}

// ---------------------------------------------------------------------------
// Kernel 1: fused QKV projection, bf16 MFMA, GLD16 ping-pong dbuf (R8,
// unchanged). z: 0=Q, 1=K (out [bh][s][d]); z=2 (V) LDS-bounce -> [bh][d][s].
// ---------------------------------------------------------------------------
#define CTP 136   // C-tile pitch: 128 + 8 pad
__global__ __launch_bounds__(256) void qkv_mfma(
    const unsigned short* __restrict__ xb,
    const unsigned short* __restrict__ wt,
    const float* __restrict__ bq, const float* __restrict__ bk,
    const float* __restrict__ bv,
    unsigned short* __restrict__ ws_out)
{
    const int bn = blockIdx.x;   // 0..7
    const int bm = blockIdx.y;   // 0..31
    const int z  = blockIdx.z;   // 0..2
    const unsigned short* Bt = wt + (size_t)z * HID * HID;
    const float* bias = (z == 0) ? bq : (z == 1) ? bk : bv;
    unsigned short* out = ws_out + (size_t)z * (size_t)BH * SEQ * HDIM;

    const int t    = threadIdx.x;
    const int wave = t >> 6;
    const int lane = t & 63;
    const int l15  = lane & 15;
    const int quad = lane >> 4;
    const int wm   = (wave >> 1) * 64;
    const int wn   = (wave & 1) * 64;

    __shared__ __align__(16) unsigned short smem[128 * CTP];
    #define ASB(buf) (smem + (buf) * 4096)
    #define BSB(buf) (smem + 8192 + (buf) * 4096)

    floatx4 acc[4][4];
    #pragma unroll
    for (int i = 0; i < 4; ++i)
        #pragma unroll
        for (int j = 0; j < 4; ++j)
            acc[i][j] = (floatx4){0.f, 0.f, 0.f, 0.f};

    const int lrow = lane >> 2;
    const int lcol = (lane & 3) * 8;

    #define QKV_STAGE(kt, buf)                                                  \
        do {                                                                    \
            _Pragma("unroll")                                                   \
            for (int ee = 0; ee < 2; ++ee) {                                    \
                const int e = wave * 2 + ee;                                    \
                const unsigned short* ga = xb +                                 \
                    (size_t)(bm * 128 + e * 16 + lrow) * HID + (kt) * 32 + lcol;\
                const unsigned short* gb = Bt +                                 \
                    (size_t)(bn * 128 + e * 16 + lrow) * HID + (kt) * 32 + lcol;\
                GLD16(ga, (char*)ASB(buf) + e * 1024);                          \
                GLD16(gb, (char*)BSB(buf) + e * 1024);                          \
            }                                                                   \
        } while (0)

    QKV_STAGE(0, 0);

    for (int kt = 0; kt < HID / 32; ++kt) {
        const int buf = kt & 1;
        __syncthreads();
        if (kt + 1 < HID / 32)
            QKV_STAGE(kt + 1, buf ^ 1);

        short8 af[4], bf[4];
        #pragma unroll
        for (int mt = 0; mt < 4; ++mt)
            af[mt] = *(const short8*)&ASB(buf)[(wm + mt * 16 + l15) * 32 + quad * 8];
        #pragma unroll
        for (int nt = 0; nt < 4; ++nt)
            bf[nt] = *(const short8*)&BSB(buf)[(wn + nt * 16 + l15) * 32 + quad * 8];
        #pragma unroll
        for (int mt = 0; mt < 4; ++mt)
            #pragma unroll
            for (int nt = 0; nt < 4; ++nt)
                acc[mt][nt] = __builtin_amdgcn_mfma_f32_16x16x32_bf16(
                    af[mt], bf[nt], acc[mt][nt], 0, 0, 0);
    }
    #undef QKV_STAGE

    if (z < 2) {
        #pragma unroll
        for (int nt = 0; nt < 4; ++nt) {
            const int n_g = bn * 128 + wn + nt * 16 + l15;
            const float bsv = bias[n_g];
            const int h = n_g >> 6;
            const int d = n_g & 63;
            #pragma unroll
            for (int mt = 0; mt < 4; ++mt) {
                #pragma unroll
                for (int r = 0; r < 4; ++r) {
                    const int m_g = bm * 128 + wm + mt * 16 + quad * 4 + r;
                    const int s  = m_g >> 1;
                    const int bb = m_g & 1;
                    out[((size_t)(bb * NHEAD + h) * SEQ + s) * HDIM + d] =
                        f2bf(acc[mt][nt][r] + bsv);
                }
            }
        }
    } else {
        __syncthreads();
        #pragma unroll
        for (int nt = 0; nt < 4; ++nt) {
            const int n_l = wn + nt * 16 + l15;
            const float bsv = bias[bn * 128 + n_l];
            #pragma unroll
            for (int mt = 0; mt < 4; ++mt) {
                #pragma unroll
                for (int r = 0; r < 4; ++r) {
                    const int m_l = wm + mt * 16 + quad * 4 + r;
                    smem[n_l * CTP + (m_l & 1) * 64 + (m_l >> 1)] =
                        f2bf(acc[mt][nt][r] + bsv);
                }
            }
        }
        __syncthreads();
        const int n_l = t >> 1;
        const int b2  = t & 1;
        const int n_g = bn * 128 + n_l;
        const int h   = n_g >> 6;
        const int d   = n_g & 63;
        const unsigned short* src = smem + n_l * CTP + b2 * 64;
        unsigned short* dst =
            out + ((size_t)(b2 * NHEAD + h) * HDIM + d) * SEQ + bm * 64;
        #pragma unroll
        for (int c = 0; c < 8; ++c)
            *(uint4*)(dst + c * 8) = *(const uint4*)(src + c * 8);
    }
}
#undef CTP

// ---------------------------------------------------------------------------
// Kernel 2a: flash attention v9 — key-split over NSPLIT grid-z halves.
// Fixed-shift softmax makes partials ADDITIVE: each half writes un-normalized
// O (frag-native float4 layout, fully coalesced) + per-row l; combine sums.
// 256 thr, 4 waves x 16 q, LDS 18.4 KB -> 8 blocks/CU; NSPLIT=2 -> 2048
// blocks = 32 waves/CU (occupancy max). Register-prefetch staging,
// in-register P (S^T C-frag == 16x16x16 A-frag).
// ---------------------------------------------------------------------------
template<int NSPLIT>
__global__ __launch_bounds__(256) void attn_v9(
    const unsigned short* __restrict__ q,
    const unsigned short* __restrict__ kp,
    const unsigned short* __restrict__ vt,
    const float* __restrict__ mask,
    float* __restrict__ po,    // [NSPLIT*32][32][256][16] fp32 frag-native
    float* __restrict__ pl)    // [NSPLIT*32][32][64] fp32 row sums
{
    const int qb   = blockIdx.x;   // 0..31 query tile (64 rows)
    const int n    = blockIdx.y;   // 0..31 flattened head
    const int half = blockIdx.z;   // 0..NSPLIT-1 key range
    const int t    = threadIdx.x;
    const int wave = t >> 6;
    const int lane = t & 63;
    const int l15  = lane & 15;
    const int quad = lane >> 4;
    const int bb   = n >> 4;       // batch

    __shared__ __align__(16) unsigned short Ks[64][KVP];   // [key][k]
    __shared__ __align__(16) unsigned short Vs[64][KVP];   // [d][key]

    const unsigned short* qbase = q + ((size_t)n * SEQ + qb * 64) * HDIM;
    short8 Qf[2];
    #pragma unroll
    for (int ks = 0; ks < 2; ++ks)
        Qf[ks] = *(const short8*)(qbase +
            (size_t)(wave * 16 + l15) * HDIM + ks * 32 + quad * 8);

    floatx4 Of[4];
    #pragma unroll
    for (int nt = 0; nt < 4; ++nt) Of[nt] = (floatx4){0.f, 0.f, 0.f, 0.f};
    float lst = 0.0f;

    const unsigned short* kbase = kp + (size_t)n * SEQ * HDIM;
    const unsigned short* vbase = vt + (size_t)n * HDIM * SEQ;
    const float* mrow = mask + ((size_t)bb * SEQ + qb * 64 + wave * 16 + l15) * SEQ;

    const int KT = (SEQ / 64) / NSPLIT;       // tiles per half
    const int kt0 = half * KT;

    const int c0 = t,        r0 = c0 >> 3, o0 = (c0 & 7) * 8;
    const int c1 = t + 256,  r1 = c1 >> 3, o1 = (c1 & 7) * 8;

    uint4 kreg0, kreg1, vreg0, vreg1;
    {   // prefetch first tile of this half
        const unsigned short* kb = kbase + (size_t)(kt0 * 64) * HDIM;
        const unsigned short* vb = vbase + kt0 * 64;
        kreg0 = *(const uint4*)(kb + (size_t)r0 * HDIM + o0);
        kreg1 = *(const uint4*)(kb + (size_t)r1 * HDIM + o1);
        vreg0 = *(const uint4*)(vb + (size_t)r0 * SEQ + o0);
        vreg1 = *(const uint4*)(vb + (size_t)r1 * SEQ + o1);
    }

    for (int kt = kt0; kt < kt0 + KT; ++kt) {
        __syncthreads();
        *(uint4*)&Ks[r0][o0] = kreg0;
        *(uint4*)&Ks[r1][o1] = kreg1;
        *(uint4*)&Vs[r0][o0] = vreg0;
        *(uint4*)&Vs[r1][o1] = vreg1;
        __syncthreads();

        if (kt + 1 < kt0 + KT) {   // prefetch next (overlaps compute)
            const unsigned short* kb = kbase + (size_t)((kt + 1) * 64) * HDIM;
            const unsigned short* vb = vbase + (kt + 1) * 64;
            kreg0 = *(const uint4*)(kb + (size_t)r0 * HDIM + o0);
            kreg1 = *(const uint4*)(kb + (size_t)r1 * HDIM + o1);
            vreg0 = *(const uint4*)(vb + (size_t)r0 * SEQ + o0);
            vreg1 = *(const uint4*)(vb + (size_t)r1 * SEQ + o1);
        }

        #pragma unroll
        for (int mt = 0; mt < 4; ++mt) {
            floatx4 c = (floatx4){0.f, 0.f, 0.f, 0.f};
            #pragma unroll
            for (int ks = 0; ks < 2; ++ks) {
                short8 a = *(const short8*)&Ks[mt * 16 + l15][ks * 32 + quad * 8];
                c = __builtin_amdgcn_mfma_f32_16x16x32_bf16(a, Qf[ks], c, 0, 0, 0);
            }

            const float4 m4 = *(const float4*)(mrow + kt * 64 + mt * 16 + quad * 4);
            const float mv[4] = {m4.x, m4.y, m4.z, m4.w};
            short4v Af;
            #pragma unroll
            for (int r = 0; r < 4; ++r) {
                const float pv = exp2f(fmaf(c[r], SCALE_LOG2E, mv[r] * LOG2E));
                lst += pv;
                Af[r] = (short)f2bf(pv);
            }

            #pragma unroll
            for (int nt = 0; nt < 4; ++nt) {
                short4v Bf = *(const short4v*)&Vs[nt * 16 + l15][mt * 16 + quad * 4];
                Of[nt] = mfma16x16x16(Af, Bf, Of[nt]);
            }
        }
    }

    // ---- partial epilogue: frag-native coalesced dump, NO normalize ----
    lst += __shfl_xor(lst, 16);
    lst += __shfl_xor(lst, 32);   // every lane: full row sum for q=l15
    const size_t bidx = ((size_t)(half * 32 + n) * 32 + qb);
    float4* pd = (float4*)(po + (bidx * 256 + t) * 16);
    #pragma unroll
    for (int nt = 0; nt < 4; ++nt) {
        float4 o; o.x = Of[nt][0]; o.y = Of[nt][1]; o.z = Of[nt][2]; o.w = Of[nt][3];
        pd[nt] = o;
    }
    if (quad == 0)
        pl[bidx * 64 + wave * 16 + l15] = lst;
}

// ---------------------------------------------------------------------------
// Kernel 2b: combine partials: out = (sum_h O_h) / (sum_h l_h), unscramble
// frag-native layout. 1M float4s, coalesced stores; reads served via L1/L2.
// ---------------------------------------------------------------------------
template<int NSPLIT>
__global__ __launch_bounds__(256) void attn_combine(
    const float* __restrict__ po, const float* __restrict__ pl,
    float* __restrict__ out)
{
    const int id = blockIdx.x * 256 + threadIdx.x;   // 0..2^20-1
    const int d4 = id & 15;
    const int h  = (id >> 4) & 15;
    const int bb = (id >> 8) & 1;
    const int s  = id >> 9;
    const int n  = bb * 16 + h;
    const int qb = s >> 6;
    const int w  = (s >> 4) & 3;
    const int quad = (s >> 2) & 3;
    const int r  = s & 3;
    const int d0 = d4 * 4;

    float acc[4] = {0.f, 0.f, 0.f, 0.f};
    float l = 0.f;
    #pragma unroll
    for (int half = 0; half < NSPLIT; ++half) {
        const size_t bidx = ((size_t)(half * 32 + n) * 32 + qb);
        const float* pb = po + (bidx * 256 + w * 64 + quad * 16) * 16;
        #pragma unroll
        for (int j = 0; j < 4; ++j) {
            const int d = d0 + j;
            acc[j] += pb[(size_t)(d & 15) * 16 + (d >> 4) * 4 + r];
        }
        l += pl[bidx * 64 + (s & 63)];
    }
    const float inv = 1.0f / l;
    float4 o;
    o.x = acc[0] * inv; o.y = acc[1] * inv; o.z = acc[2] * inv; o.w = acc[3] * inv;
    ((float4*)out)[id] = o;
}

// ---------------------------------------------------------------------------
extern "C" void kernel_launch(void* const* d_in, const int* in_sizes, int n_in,
                              void* d_out, int out_size, void* d_ws, size_t ws_size,
                              hipStream_t stream) {
    const float* x    = (const float*)d_in[0];
    const float* mask = (const float*)d_in[1];
    const float* Wq   = (const float*)d_in[2];
    const float* bq   = (const float*)d_in[3];
    const float* Wk   = (const float*)d_in[4];
    const float* bk   = (const float*)d_in[5];
    const float* Wv   = (const float*)d_in[6];
    const float* bv   = (const float*)d_in[7];
    float* out = (float*)d_out;

    const size_t per = (size_t)BH * SEQ * HDIM;   // 4,194,304 elems (8 MB bf16)
    unsigned short* qw = (unsigned short*)d_ws;   // [0, 8) MB
    unsigned short* kw = qw + per;                // [8,16) MB
    unsigned short* vw = kw + per;                // [16,24) MB (V^T [bh][d][s])
    unsigned short* xb = vw + per;                // [24,32) MB, dead after qkv
    unsigned short* wt = xb + per;                // [32,38) MB, dead after qkv

    // attention partials overlap xb/wt (written only after qkv completes)
    const size_t PO_OFF = 3 * per * sizeof(unsigned short);   // 24 MB
    float* po = (float*)((char*)d_ws + PO_OFF);
    const size_t po_elems2 = (size_t)2 * 32 * 32 * 256 * 16;  // 33.55 MB
    float* pl2 = po + po_elems2;
    const size_t need2 = PO_OFF + (po_elems2 + (size_t)2 * 32 * 32 * 64) * 4;

    convert_x<<<dim3(SEQ * BATCH * HID / 4 / 256), dim3(256), 0, stream>>>(x, xb);
    transpose_w<<<dim3(32, 32, 3), dim3(256), 0, stream>>>(Wq, Wk, Wv, wt);

    qkv_mfma<<<dim3(HID / 128, SEQ * BATCH / 128, 3), dim3(256), 0, stream>>>(
        xb, wt, bq, bk, bv, qw);

    if (ws_size >= need2) {
        attn_v9<2><<<dim3(SEQ / 64, BH, 2), dim3(256), 0, stream>>>(
            qw, kw, vw, mask, po, pl2);
        attn_combine<2><<<dim3(SEQ * BATCH * HID / 4 / 256), dim3(256), 0, stream>>>(
            po, pl2, out);
    } else {
        // fallback: single split (needs 16.8 MB past 24 MB = 41 MB)
        const size_t po_elems1 = (size_t)32 * 32 * 256 * 16;
        float* pl1 = po + po_elems1;
        attn_v9<1><<<dim3(SEQ / 64, BH, 1), dim3(256), 0, stream>>>(
            qw, kw, vw, mask, po, pl1);
        attn_combine<1><<<dim3(SEQ * BATCH * HID / 4 / 256), dim3(256), 0, stream>>>(
            po, pl1, out);
    }
}

// Round 11
// 253.723 us; speedup vs baseline: 1.0365x; 1.0365x over previous
//
#include <hip/hip_runtime.h>
#include <hip/hip_bf16.h>

// Problem constants (BertSelfAttention_979252544303)
#define SEQ   2048
#define BATCH 2
#define HID   1024
#define NHEAD 16
#define HDIM  64
#define BH    (BATCH * NHEAD)   // 32 flattened heads

using short4v  = __attribute__((ext_vector_type(4))) short;
using short8   = __attribute__((ext_vector_type(8))) short;
using floatx4  = __attribute__((ext_vector_type(4))) float;

#define LOG2E 1.44269504f
#define SCALE_LOG2E (0.125f * LOG2E)   // (1/sqrt(64)) * log2(e)

// attn LDS pitch 72 (pitch 80 doubled SQ_LDS_BANK_CONFLICT — measured R8;
// conflicts are off the critical path at this occupancy anyway)
#define KVP 72

// float -> bf16 (RNE)
static __device__ __forceinline__ unsigned short f2bf(float f) {
    unsigned int u = __builtin_bit_cast(unsigned int, f);
    u += 0x7fffu + ((u >> 16) & 1u);
    return (unsigned short)(u >> 16);
}

// D = A(16x16 bf16) * B(16x16 bf16) + C  — per-wave MFMA, K=16
static __device__ __forceinline__ floatx4 mfma16x16x16(
    short4v a, short4v b, floatx4 c) {
#if __has_builtin(__builtin_amdgcn_mfma_f32_16x16x16bf16_1k)
    return __builtin_amdgcn_mfma_f32_16x16x16bf16_1k(a, b, c, 0, 0, 0);
#else
    floatx4 d;
    asm volatile("v_mfma_f32_16x16x16_bf16 %0, %1, %2, %3"
                 : "=v"(d) : "v"(a), "v"(b), "v"(c));
    return d;
#endif
}

#define GLD16(gp, lp)                                                        \
    __builtin_amdgcn_global_load_lds(                                        \
        (const __attribute__((address_space(1))) void*)(gp),                 \
        (__attribute__((address_space(3))) void*)(lp), 16, 0, 0)

// ---------------------------------------------------------------------------
// Prep 1: x fp32 [4096][1024] -> bf16 (straight). 1 float4 per thread.
// ---------------------------------------------------------------------------
__global__ __launch_bounds__(256) void convert_x(
    const float* __restrict__ x, unsigned short* __restrict__ xb)
{
    const int i = blockIdx.x * 256 + threadIdx.x;
    const float4 v = ((const float4*)x)[i];
    ushort4 o;
    o.x = f2bf(v.x); o.y = f2bf(v.y); o.z = f2bf(v.z); o.w = f2bf(v.w);
    ((ushort4*)xb)[i] = o;
}

// ---------------------------------------------------------------------------
// Prep 2: W fp32 [k][n] -> wt bf16 [n][k], tiled transpose. z selects Q/K/V.
// ---------------------------------------------------------------------------
__global__ __launch_bounds__(256) void transpose_w(
    const float* __restrict__ Wq, const float* __restrict__ Wk,
    const float* __restrict__ Wv, unsigned short* __restrict__ wt)
{
    const float* W = (blockIdx.z == 0) ? Wq : (blockIdx.z == 1) ? Wk : Wv;
    unsigned short* out = wt + (size_t)blockIdx.z * HID * HID;
    __shared__ float tile[32][33];
    const int tx = threadIdx.x & 31, ty = threadIdx.x >> 5;
    const int bx = blockIdx.x * 32, by = blockIdx.y * 32;
    #pragma unroll
    for (int j = 0; j < 4; ++j)
        tile[ty + j * 8][tx] = W[(size_t)(by + ty + j * 8) * HID + bx + tx];
    __syncthreads();
    #pragma unroll
    for (int j = 0; j < 4; ++j)
        out[(size_t)(bx + ty + j * 8) * HID + by + tx] = f2bf(tile[tx][ty + j * 8]);
}

// ---------------------------------------------------------------------------
// Kernel 1: fused QKV projection v3 — 128x64 (MxN) tiles, BK=32, GLD16
// ping-pong dbuf. Grid 32x16x3 = 1536 blocks = 6 blocks/CU = 24 waves/CU
// (was 128x128 / 768 blocks / 3 per CU: per-iter DMA stalls unhidden at
// that occupancy — K=1024 gives only 32 iters to amortize).
// Each wave owns a 32x64 sub-tile: 2x4 16x16x32 frags, 8 MFMA/iter.
// z: 0=Q, 1=K -> out [bh][s][d]; z=2 (V) LDS-bounce -> [bh][d][s] with
// full-128B-line dwordx4 stores.
// ---------------------------------------------------------------------------
#define CTP 136   // V-epilogue C-tile pitch: 128 + 8 pad
__global__ __launch_bounds__(256) void qkv_mfma(
    const unsigned short* __restrict__ xb,
    const unsigned short* __restrict__ wt,
    const float* __restrict__ bq, const float* __restrict__ bk,
    const float* __restrict__ bv,
    unsigned short* __restrict__ ws_out)
{
    const int bn = blockIdx.x;   // 0..15 (64-col tile)
    const int bm = blockIdx.y;   // 0..31 (128-row tile)
    const int z  = blockIdx.z;   // 0..2
    const unsigned short* Bt = wt + (size_t)z * HID * HID;
    const float* bias = (z == 0) ? bq : (z == 1) ? bk : bv;
    unsigned short* out = ws_out + (size_t)z * (size_t)BH * SEQ * HDIM;

    const int t    = threadIdx.x;
    const int wave = t >> 6;
    const int lane = t & 63;
    const int l15  = lane & 15;
    const int quad = lane >> 4;
    const int wm   = wave * 32;           // wave's 32-row band

    // union: A dbuf 2x4096 shorts + B dbuf 2x2048 shorts = 12288 shorts
    // (24.6 KB); V-epilogue C tile needs 64*CTP = 8704 shorts (reuses front).
    __shared__ __align__(16) unsigned short smem[12288];
    #define ASB(buf) (smem + (buf) * 4096)
    #define BSB(buf) (smem + 8192 + (buf) * 2048)

    floatx4 acc[2][4];
    #pragma unroll
    for (int i = 0; i < 2; ++i)
        #pragma unroll
        for (int j = 0; j < 4; ++j)
            acc[i][j] = (floatx4){0.f, 0.f, 0.f, 0.f};

    const int lrow = lane >> 2;          // 0..15 row within 16-row chunk
    const int lcol = (lane & 3) * 8;     // k-col: 0,8,16,24

    // A: 8 chunks of 16 rows (e = wave*2+ee); B: 4 chunks (e2 = wave).
    #define QKV_STAGE(kt, buf)                                                  \
        do {                                                                    \
            _Pragma("unroll")                                                   \
            for (int ee = 0; ee < 2; ++ee) {                                    \
                const int e = wave * 2 + ee;                                    \
                const unsigned short* ga = xb +                                 \
                    (size_t)(bm * 128 + e * 16 + lrow) * HID + (kt) * 32 + lcol;\
                GLD16(ga, (char*)ASB(buf) + e * 1024);                          \
            }                                                                   \
            const unsigned short* gb = Bt +                                     \
                (size_t)(bn * 64 + wave * 16 + lrow) * HID + (kt) * 32 + lcol;  \
            GLD16(gb, (char*)BSB(buf) + wave * 1024);                           \
        } while (0)

    QKV_STAGE(0, 0);

    for (int kt = 0; kt < HID / 32; ++kt) {
        const int buf = kt & 1;
        __syncthreads();   // drains DMA for tile kt (issued a full phase ago)
        if (kt + 1 < HID / 32)
            QKV_STAGE(kt + 1, buf ^ 1);   // overlaps with compute below

        short8 af[2], bf[4];
        #pragma unroll
        for (int mt = 0; mt < 2; ++mt)
            af[mt] = *(const short8*)&ASB(buf)[(wm + mt * 16 + l15) * 32 + quad * 8];
        #pragma unroll
        for (int nt = 0; nt < 4; ++nt)
            bf[nt] = *(const short8*)&BSB(buf)[(nt * 16 + l15) * 32 + quad * 8];
        #pragma unroll
        for (int mt = 0; mt < 2; ++mt)
            #pragma unroll
            for (int nt = 0; nt < 4; ++nt)
                acc[mt][nt] = __builtin_amdgcn_mfma_f32_16x16x32_bf16(
                    af[mt], bf[nt], acc[mt][nt], 0, 0, 0);
    }
    #undef QKV_STAGE

    if (z < 2) {
        #pragma unroll
        for (int nt = 0; nt < 4; ++nt) {
            const int n_g = bn * 64 + nt * 16 + l15;
            const float bsv = bias[n_g];
            const int h = n_g >> 6;
            const int d = n_g & 63;
            #pragma unroll
            for (int mt = 0; mt < 2; ++mt) {
                #pragma unroll
                for (int r = 0; r < 4; ++r) {
                    const int m_g = bm * 128 + wm + mt * 16 + quad * 4 + r;
                    const int s  = m_g >> 1;
                    const int bb = m_g & 1;
                    out[((size_t)(bb * NHEAD + h) * SEQ + s) * HDIM + d] =
                        f2bf(acc[mt][nt][r] + bsv);
                }
            }
        }
    } else {
        // ---- V: LDS bounce -> coalesced [bh][d][s] full-line stores ----
        __syncthreads();   // all frag reads from smem complete before reuse
        #pragma unroll
        for (int nt = 0; nt < 4; ++nt) {
            const int n_l = nt * 16 + l15;           // 0..63 within col tile
            const float bsv = bias[bn * 64 + n_l];
            #pragma unroll
            for (int mt = 0; mt < 2; ++mt) {
                #pragma unroll
                for (int r = 0; r < 4; ++r) {
                    const int m_l = wm + mt * 16 + quad * 4 + r;   // 0..127
                    smem[n_l * CTP + (m_l & 1) * 64 + (m_l >> 1)] =
                        f2bf(acc[mt][nt][r] + bsv);
                }
            }
        }
        __syncthreads();
        // read back: 128 rows (n_l, b2) x 64 shorts; 2 threads per row
        const int rowid = t >> 1;          // 0..127
        const int n_l   = rowid >> 1;      // 0..63
        const int b2    = rowid & 1;
        const int hhalf = t & 1;           // which 64-B half of the row
        const int n_g   = bn * 64 + n_l;
        const int h     = n_g >> 6;
        const int d     = n_g & 63;
        const unsigned short* src = smem + n_l * CTP + b2 * 64 + hhalf * 32;
        unsigned short* dst =
            out + ((size_t)(b2 * NHEAD + h) * HDIM + d) * SEQ + bm * 64 + hhalf * 32;
        #pragma unroll
        for (int c = 0; c < 4; ++c)    // 4 x 16B = 64 B per thread
            *(uint4*)(dst + c * 8) = *(const uint4*)(src + c * 8);
    }
}
#undef CTP

// ---------------------------------------------------------------------------
// Kernel 2: flash attention v8 (reverted R9 split — it didn't raise
// occupancy and the combine cost ~30 µs). 256 threads, 4 waves x 16 q-rows,
// grid (32 qb, 32 heads) = 1024 blocks. Register-prefetch staging,
// in-register P (S^T C-frag == 16x16x16 A-frag), fixed-shift softmax.
// q,kp: [bh][s][d] bf16; vt: [bh][d][s] bf16; mask: [B][1][S][S] fp32.
// ---------------------------------------------------------------------------
__global__ __launch_bounds__(256) void attn_v8(
    const unsigned short* __restrict__ q,
    const unsigned short* __restrict__ kp,
    const unsigned short* __restrict__ vt,
    const float* __restrict__ mask,
    float* __restrict__ out)
{
    const int qb   = blockIdx.x;   // 0..31 query tile (64 rows)
    const int n    = blockIdx.y;   // 0..31 flattened head
    const int t    = threadIdx.x;
    const int wave = t >> 6;
    const int lane = t & 63;
    const int l15  = lane & 15;
    const int quad = lane >> 4;
    const int bb   = n >> 4;       // batch
    const int hh   = n & 15;       // head

    __shared__ __align__(16) unsigned short Ks[64][KVP];   // [key][k]
    __shared__ __align__(16) unsigned short Vs[64][KVP];   // [d][key]

    // ---- Q fragments straight from global (one-time) ----
    const unsigned short* qbase = q + ((size_t)n * SEQ + qb * 64) * HDIM;
    short8 Qf[2];
    #pragma unroll
    for (int ks = 0; ks < 2; ++ks)
        Qf[ks] = *(const short8*)(qbase +
            (size_t)(wave * 16 + l15) * HDIM + ks * 32 + quad * 8);

    floatx4 Of[4];
    #pragma unroll
    for (int nt = 0; nt < 4; ++nt) Of[nt] = (floatx4){0.f, 0.f, 0.f, 0.f};
    float lst = 0.0f;

    const unsigned short* kbase = kp + (size_t)n * SEQ * HDIM;
    const unsigned short* vbase = vt + (size_t)n * HDIM * SEQ;
    const float* mrow = mask + ((size_t)bb * SEQ + qb * 64 + wave * 16 + l15) * SEQ;

    const int c0 = t,        r0 = c0 >> 3, o0 = (c0 & 7) * 8;
    const int c1 = t + 256,  r1 = c1 >> 3, o1 = (c1 & 7) * 8;

    uint4 kreg0, kreg1, vreg0, vreg1;
    {   // prefetch tile 0
        kreg0 = *(const uint4*)(kbase + (size_t)r0 * HDIM + o0);
        kreg1 = *(const uint4*)(kbase + (size_t)r1 * HDIM + o1);
        vreg0 = *(const uint4*)(vbase + (size_t)r0 * SEQ + o0);
        vreg1 = *(const uint4*)(vbase + (size_t)r1 * SEQ + o1);
    }

    for (int kt = 0; kt < SEQ / 64; ++kt) {
        __syncthreads();   // previous K/V tile fully consumed
        *(uint4*)&Ks[r0][o0] = kreg0;
        *(uint4*)&Ks[r1][o1] = kreg1;
        *(uint4*)&Vs[r0][o0] = vreg0;
        *(uint4*)&Vs[r1][o1] = vreg1;
        __syncthreads();   // tile kt visible to all waves

        if (kt + 1 < SEQ / 64) {   // prefetch kt+1 (overlaps compute below)
            const unsigned short* kb = kbase + (size_t)((kt + 1) * 64) * HDIM;
            const unsigned short* vb = vbase + (kt + 1) * 64;
            kreg0 = *(const uint4*)(kb + (size_t)r0 * HDIM + o0);
            kreg1 = *(const uint4*)(kb + (size_t)r1 * HDIM + o1);
            vreg0 = *(const uint4*)(vb + (size_t)r0 * SEQ + o0);
            vreg1 = *(const uint4*)(vb + (size_t)r1 * SEQ + o1);
        }

        // per 16-key subtile: S^T MFMA -> softmax -> in-register P -> PV
        #pragma unroll
        for (int mt = 0; mt < 4; ++mt) {
            floatx4 c = (floatx4){0.f, 0.f, 0.f, 0.f};
            #pragma unroll
            for (int ks = 0; ks < 2; ++ks) {
                short8 a = *(const short8*)&Ks[mt * 16 + l15][ks * 32 + quad * 8];
                c = __builtin_amdgcn_mfma_f32_16x16x32_bf16(a, Qf[ks], c, 0, 0, 0);
            }

            const float4 m4 = *(const float4*)(mrow + kt * 64 + mt * 16 + quad * 4);
            const float mv[4] = {m4.x, m4.y, m4.z, m4.w};
            short4v Af;
            #pragma unroll
            for (int r = 0; r < 4; ++r) {
                const float pv = exp2f(fmaf(c[r], SCALE_LOG2E, mv[r] * LOG2E));
                lst += pv;
                Af[r] = (short)f2bf(pv);
            }

            #pragma unroll
            for (int nt = 0; nt < 4; ++nt) {
                short4v Bf = *(const short4v*)&Vs[nt * 16 + l15][mt * 16 + quad * 4];
                Of[nt] = mfma16x16x16(Af, Bf, Of[nt]);
            }
        }
    }

    // ---- epilogue: reduce l across quads, normalize, store ----
    lst += __shfl_xor(lst, 16);
    lst += __shfl_xor(lst, 32);   // lane with l15=q now holds full row sum
    #pragma unroll
    for (int r = 0; r < 4; ++r) {
        const float lrow = __shfl(lst, quad * 4 + r);   // row q = quad*4+r
        const float inv  = 1.0f / lrow;
        const int s = qb * 64 + wave * 16 + quad * 4 + r;
        float* orow = out + ((size_t)s * BATCH + bb) * HID + hh * 64;
        #pragma unroll
        for (int nt = 0; nt < 4; ++nt)
            orow[nt * 16 + l15] = Of[nt][r] * inv;
    }
}

// ---------------------------------------------------------------------------
extern "C" void kernel_launch(void* const* d_in, const int* in_sizes, int n_in,
                              void* d_out, int out_size, void* d_ws, size_t ws_size,
                              hipStream_t stream) {
    const float* x    = (const float*)d_in[0];
    const float* mask = (const float*)d_in[1];
    const float* Wq   = (const float*)d_in[2];
    const float* bq   = (const float*)d_in[3];
    const float* Wk   = (const float*)d_in[4];
    const float* bk   = (const float*)d_in[5];
    const float* Wv   = (const float*)d_in[6];
    const float* bv   = (const float*)d_in[7];
    float* out = (float*)d_out;

    const size_t per = (size_t)BH * SEQ * HDIM;   // 4,194,304 elems (8 MB bf16)
    unsigned short* qw = (unsigned short*)d_ws;   // 8 MB
    unsigned short* kw = qw + per;                // 8 MB
    unsigned short* vw = kw + per;                // 8 MB (V transposed [bh][d][s])
    unsigned short* xb = vw + per;                // 8 MB (x bf16)
    unsigned short* wt = xb + per;                // 6 MB (3x W^T bf16)

    convert_x<<<dim3(SEQ * BATCH * HID / 4 / 256), dim3(256), 0, stream>>>(x, xb);
    transpose_w<<<dim3(32, 32, 3), dim3(256), 0, stream>>>(Wq, Wk, Wv, wt);

    qkv_mfma<<<dim3(HID / 64, SEQ * BATCH / 128, 3), dim3(256), 0, stream>>>(
        xb, wt, bq, bk, bv, qw);

    attn_v8<<<dim3(SEQ / 64, BH), dim3(256), 0, stream>>>(qw, kw, vw, mask, out);
}